// Round 1
// baseline (483.006 us; speedup 1.0000x reference)
//
#include <hip/hip_runtime.h>
#include <hip/hip_bf16.h>

typedef unsigned short ushort_t;
typedef __attribute__((ext_vector_type(4))) float v4f;
typedef __attribute__((ext_vector_type(8))) short v8s;

#define FDIM 128
#define KCLUST 16

__device__ __forceinline__ ushort_t f2bf(float x) {
    unsigned int u = __float_as_uint(x);
    unsigned int r = (u + 0x7fffu + ((u >> 16) & 1u)) >> 16;
    return (ushort_t)r;
}

__device__ __forceinline__ float wave_reduce_sum(float v) {
    #pragma unroll
    for (int off = 32; off > 0; off >>= 1) v += __shfl_xor(v, off, 64);
    return v;
}

__device__ __forceinline__ void gl2lds16(const void* g, void* l) {
    __builtin_amdgcn_global_load_lds(
        (const __attribute__((address_space(1))) void*)g,
        (__attribute__((address_space(3))) void*)l, 16, 0, 0);
}

// ---------------------------------------------------------------------------
// Kernel 1: cast weight (E x 256 f32) -> bf16, padded to Np rows (zeros).
// ---------------------------------------------------------------------------
__global__ void pack_weight(const float* __restrict__ W, ushort_t* __restrict__ Wb,
                            long total, long valid) {
    long i = ((long)blockIdx.x * blockDim.x + threadIdx.x) * 4;
    if (i >= total) return;
    float4 v;
    if (i < valid) v = *(const float4*)(W + i);
    else           v = make_float4(0.f, 0.f, 0.f, 0.f);
    ushort_t* dst = Wb + i;
    dst[0] = f2bf(v.x); dst[1] = f2bf(v.y); dst[2] = f2bf(v.z); dst[3] = f2bf(v.w);
}

// ---------------------------------------------------------------------------
// Kernel 2: build combined = [self_feat | neigh_agg] as bf16, Mp x 256,
// one wave (64 lanes) per row b; lane l owns features l and l+64.
// ---------------------------------------------------------------------------
__global__ __launch_bounds__(256) void build_combined(
    const int* __restrict__ nodes, const int* __restrict__ neigh_idx,
    const float* __restrict__ self_table, const float* __restrict__ neigh_table,
    const float* __restrict__ center, const float* __restrict__ cluster_mask,
    const float* __restrict__ alpha, ushort_t* __restrict__ Ab,
    int B, int S, int Mp) {
    __shared__ float cLds[KCLUST * FDIM];
    __shared__ float mLds[KCLUST * FDIM];
    __shared__ float c2Lds[KCLUST];
    int t = threadIdx.x;
    for (int i = t; i < KCLUST * FDIM; i += 256) {
        cLds[i] = center[i];
        mLds[i] = cluster_mask[i];
    }
    __syncthreads();
    if (t < KCLUST) {
        float s = 0.f;
        for (int f = 0; f < FDIM; f++) { float c = cLds[t * FDIM + f]; s += c * c; }
        c2Lds[t] = s;
    }
    __syncthreads();

    int wave = t >> 6, lane = t & 63;
    long b = (long)blockIdx.x * 4 + wave;
    if (b >= Mp) return;
    ushort_t* row = Ab + b * 256;
    if (b >= B) {  // zero padding rows
        row[lane] = 0; row[lane + 64] = 0; row[lane + 128] = 0; row[lane + 192] = 0;
        return;
    }

    float as0 = alpha[lane],        as1 = alpha[lane + 64];
    float an0 = alpha[128 + lane],  an1 = alpha[192 + lane];

    long node = nodes[b];
    float s0 = self_table[node * FDIM + lane];
    float s1 = self_table[node * FDIM + lane + 64];
    float logit_self = wave_reduce_sum(s0 * as0 + s1 * as1);

    float acc0 = 0.f, acc1 = 0.f, attsum = 0.f;
    for (int s = 0; s < S; s++) {
        long g = neigh_idx[b * S + s];
        float n0 = neigh_table[g * FDIM + lane];
        float n1 = neigh_table[g * FDIM + lane + 64];
        float ln = wave_reduce_sum(n0 * an0 + n1 * an1);
        float att = expf(fmaxf(logit_self + ln, 0.f));
        float n2 = wave_reduce_sum(n0 * n0 + n1 * n1);
        float q[KCLUST];
        #pragma unroll
        for (int k = 0; k < KCLUST; k++) {
            float p = n0 * cLds[k * FDIM + lane] + n1 * cLds[k * FDIM + 64 + lane];
            float cross = wave_reduce_sum(p);
            q[k] = 1.f / (n2 - 2.f * cross + c2Lds[k] + 1.f);
        }
        float m0 = 0.f, m1 = 0.f;
        #pragma unroll
        for (int k = 0; k < KCLUST; k++) {
            m0 += q[k] * mLds[k * FDIM + lane];
            m1 += q[k] * mLds[k * FDIM + 64 + lane];
        }
        acc0 += att * n0 * m0;
        acc1 += att * n1 * m1;
        attsum += att;
    }
    float inv = 1.f / attsum;
    row[lane]       = f2bf(s0);
    row[lane + 64]  = f2bf(s1);
    row[lane + 128] = f2bf(acc0 * inv);
    row[lane + 192] = f2bf(acc1 * inv);
}

// ---------------------------------------------------------------------------
// Kernel 3: C[M,N] = relu(A[M,256] @ Bm[N,256]^T), bf16 in, f32 out.
// 128x128 tile, BK=64, 4 waves, each wave 4x4 frags of 16x16x32 MFMA.
// ---------------------------------------------------------------------------
__global__ __launch_bounds__(256, 2) void gemm_bt(
    const ushort_t* __restrict__ A, const ushort_t* __restrict__ Bm,
    float* __restrict__ C, int M, int N) {
    __shared__ ushort_t As[128 * 64];
    __shared__ ushort_t Bs[128 * 64];

    int t = threadIdx.x;
    int lane = t & 63, wave = t >> 6;
    int quad = lane >> 4, l16 = lane & 15;
    int wm = wave & 1, wn = wave >> 1;
    int bm = blockIdx.x, bn = blockIdx.y;

    v4f acc[4][4] = {};

    #pragma unroll
    for (int ks = 0; ks < 256; ks += 64) {
        #pragma unroll
        for (int p = 0; p < 4; p++) {
            int off = p * 4096 + t * 16;      // byte offset in LDS tile
            int idx = off >> 1;               // ushort index
            int r = idx >> 6, c = idx & 63;
            gl2lds16(A + ((size_t)(bm * 128 + r)) * 256 + ks + c, (char*)As + off);
            gl2lds16(Bm + ((size_t)(bn * 128 + r)) * 256 + ks + c, (char*)Bs + off);
        }
        __syncthreads();
        #pragma unroll
        for (int kk = 0; kk < 64; kk += 32) {
            v8s a[4], b[4];
            #pragma unroll
            for (int i = 0; i < 4; i++) {
                a[i] = *(const v8s*)&As[(wm * 64 + i * 16 + l16) * 64 + kk + quad * 8];
                b[i] = *(const v8s*)&Bs[(wn * 64 + i * 16 + l16) * 64 + kk + quad * 8];
            }
            #pragma unroll
            for (int mi = 0; mi < 4; mi++)
                #pragma unroll
                for (int ni = 0; ni < 4; ni++)
                    acc[mi][ni] = __builtin_amdgcn_mfma_f32_16x16x32_bf16(
                        a[mi], b[ni], acc[mi][ni], 0, 0, 0);
        }
        __syncthreads();
    }

    size_t Nl = (size_t)N;
    #pragma unroll
    for (int mi = 0; mi < 4; mi++) {
        #pragma unroll
        for (int r = 0; r < 4; r++) {
            int grow = bm * 128 + wm * 64 + mi * 16 + quad * 4 + r;
            if (grow >= M) continue;
            float* cp = C + (size_t)grow * Nl;
            #pragma unroll
            for (int ni = 0; ni < 4; ni++) {
                int gcol = bn * 128 + wn * 64 + ni * 16 + l16;
                if (gcol < N) cp[gcol] = fmaxf(acc[mi][ni][r], 0.f);
            }
        }
    }
}

extern "C" void kernel_launch(void* const* d_in, const int* in_sizes, int n_in,
                              void* d_out, int out_size, void* d_ws, size_t ws_size,
                              hipStream_t stream) {
    const int*   nodes        = (const int*)d_in[0];
    const int*   neigh_idx    = (const int*)d_in[1];
    const float* self_table   = (const float*)d_in[2];
    const float* neigh_table  = (const float*)d_in[3];
    const float* center       = (const float*)d_in[4];
    const float* cluster_mask = (const float*)d_in[5];
    const float* weight       = (const float*)d_in[6];
    const float* alpha        = (const float*)d_in[7];
    float* out = (float*)d_out;

    int B = in_sizes[0];
    int S = in_sizes[1] / B;
    int E = in_sizes[6] / (2 * FDIM);

    int Mp = ((B + 127) / 128) * 128;   // 20096
    int Np = ((E + 127) / 128) * 128;   // 200064

    ushort_t* Wb = (ushort_t*)d_ws;                  // Np x 256 bf16
    ushort_t* Ab = Wb + (size_t)Np * 256;            // Mp x 256 bf16

    long totalW = (long)Np * 256;
    long validW = (long)E * 256;
    int blksW = (int)((totalW + 1023) / 1024);
    pack_weight<<<blksW, 256, 0, stream>>>(weight, Wb, totalW, validW);

    build_combined<<<Mp / 4, 256, 0, stream>>>(
        nodes, neigh_idx, self_table, neigh_table, center, cluster_mask, alpha,
        Ab, B, S, Mp);

    dim3 grid(Mp / 128, Np / 128);
    gemm_bt<<<grid, 256, 0, stream>>>(Ab, Wb, out, B, E);
}

// Round 2
// 279.886 us; speedup vs baseline: 1.7257x; 1.7257x over previous
//
#include <hip/hip_runtime.h>
#include <hip/hip_bf16.h>

typedef unsigned short ushort_t;
typedef __attribute__((ext_vector_type(4))) float v4f;
typedef __attribute__((ext_vector_type(8))) short v8s;

#define FDIM 128
#define KCLUST 16
#define CSTRIDE 264   // combined-row stride in bf16 elems (264*2B = 528B -> rows offset by 4 banks)

__device__ __forceinline__ ushort_t f2bf(float x) {
    unsigned int u = __float_as_uint(x);
    unsigned int r = (u + 0x7fffu + ((u >> 16) & 1u)) >> 16;
    return (ushort_t)r;
}

__device__ __forceinline__ float wave_reduce_sum(float v) {
    #pragma unroll
    for (int off = 32; off > 0; off >>= 1) v += __shfl_xor(v, off, 64);
    return v;
}

// ---------------------------------------------------------------------------
// Kernel 1: cast weight (E x 256 f32) -> bf16, padded to Np rows (zeros).
// ---------------------------------------------------------------------------
__global__ void pack_weight(const float* __restrict__ W, ushort_t* __restrict__ Wb,
                            long total, long valid) {
    long i = ((long)blockIdx.x * blockDim.x + threadIdx.x) * 4;
    if (i >= total) return;
    float4 v;
    if (i < valid) v = *(const float4*)(W + i);
    else           v = make_float4(0.f, 0.f, 0.f, 0.f);
    ushort_t* dst = Wb + i;
    dst[0] = f2bf(v.x); dst[1] = f2bf(v.y); dst[2] = f2bf(v.z); dst[3] = f2bf(v.w);
}

// ---------------------------------------------------------------------------
// Kernel 2 (fused): per block of 16 rows b:
//   phase A: build combined[16][256] bf16 in LDS (1 wave = 4 rows, sequential).
//     - neighbor vec staged in per-wave swizzled LDS buffer, re-read in
//       (cluster k, feature-block) lane layout; d_k = sum (n-c_k)^2 computed
//       with center in VGPRs; only 2 shuffles per (b,s) for the blk-reduce
//       plus one 6-step butterfly for the attention logit.
//   phase B: out[16][E] = relu(combined @ Wb^T) via mfma 16x16x32 bf16,
//     W fragments loaded directly from global (64 KB, L2-resident).
// ---------------------------------------------------------------------------
__global__ __launch_bounds__(256) void fused_agg(
    const int* __restrict__ nodes, const int* __restrict__ neigh_idx,
    const float* __restrict__ self_table, const float* __restrict__ neigh_table,
    const float* __restrict__ center, const float* __restrict__ cluster_mask,
    const float* __restrict__ alpha, const ushort_t* __restrict__ Wb,
    float* __restrict__ out, int B, int S, int E) {

    __shared__ __align__(16) ushort_t comb[16 * CSTRIDE];
    __shared__ __align__(16) float nbuf[4 * 144];   // per-wave swizzled neigh vec
    __shared__ __align__(16) float qbuf[4 * 16];    // per-wave q[16]

    int t = threadIdx.x;
    int lane = t & 63, wave = t >> 6;
    int kcl = lane & 15, blk = lane >> 4;   // cluster-layout lane id
    int l16 = lane & 15, quad = lane >> 4;  // mfma-layout lane id (same split)

    // per-lane constants (feature layout: this lane owns features lane, lane+64)
    float as0 = alpha[lane],       as1 = alpha[lane + 64];
    float an0 = alpha[128 + lane], an1 = alpha[192 + lane];

    // center in cluster layout: cc[j] = center[kcl][blk*32 + j]
    float cc[32];
    {
        const float* cb = center + kcl * FDIM + blk * 32;
        #pragma unroll
        for (int j = 0; j < 32; j += 4) {
            float4 v = *(const float4*)(cb + j);
            cc[j] = v.x; cc[j+1] = v.y; cc[j+2] = v.z; cc[j+3] = v.w;
        }
    }
    // mask in feature layout: mk0[k] = mask[k][lane], mk1[k] = mask[k][lane+64]
    float mk0[KCLUST], mk1[KCLUST];
    #pragma unroll
    for (int kk = 0; kk < KCLUST; kk++) {
        mk0[kk] = cluster_mask[kk * FDIM + lane];
        mk1[kk] = cluster_mask[kk * FDIM + 64 + lane];
    }

    int b0 = blockIdx.x * 16;
    float* nb = nbuf + wave * 144;
    float* qb = qbuf + wave * 16;

    // ---------------- phase A ----------------
    for (int r = 0; r < 4; r++) {
        int row = wave * 4 + r;
        int b = b0 + row;
        ushort_t* crow = comb + row * CSTRIDE;
        if (b >= B) {
            crow[lane] = 0; crow[lane + 64] = 0;
            crow[lane + 128] = 0; crow[lane + 192] = 0;
            continue;
        }
        size_t node = (size_t)nodes[b];
        float s0 = self_table[node * FDIM + lane];
        float s1 = self_table[node * FDIM + 64 + lane];
        float logit_self = wave_reduce_sum(s0 * as0 + s1 * as1);

        float acc0 = 0.f, acc1 = 0.f, attsum = 0.f;
        // software pipeline: preload neighbor s=0
        size_t g = (size_t)neigh_idx[(size_t)b * S];
        float n0 = neigh_table[g * FDIM + lane];
        float n1 = neigh_table[g * FDIM + 64 + lane];
        for (int s = 0; s < S; s++) {
            float cn0 = n0, cn1 = n1;
            if (s + 1 < S) {
                g = (size_t)neigh_idx[(size_t)b * S + s + 1];
                n0 = neigh_table[g * FDIM + lane];
                n1 = neigh_table[g * FDIM + 64 + lane];
            }
            // attention logit (one butterfly)
            float ln = wave_reduce_sum(cn0 * an0 + cn1 * an1);
            float att = __expf(fmaxf(logit_self + ln, 0.f));
            // stage neigh vec (swizzled: float f at idx f + (f>>5)*4)
            nb[lane + (lane >> 5) * 4] = cn0;
            int f2 = lane + 64;
            nb[f2 + (f2 >> 5) * 4] = cn1;
            // cluster layout: d_k = sum_j (n_j - c_kj)^2 over this blk's 32 feats
            float d = 0.f;
            const float* nbb = nb + blk * 36;
            #pragma unroll
            for (int i = 0; i < 8; i++) {
                float4 f4 = *(const float4*)(nbb + i * 4);
                float t0 = f4.x - cc[i*4+0]; d = fmaf(t0, t0, d);
                float t1 = f4.y - cc[i*4+1]; d = fmaf(t1, t1, d);
                float t2 = f4.z - cc[i*4+2]; d = fmaf(t2, t2, d);
                float t3 = f4.w - cc[i*4+3]; d = fmaf(t3, t3, d);
            }
            d += __shfl_xor(d, 16, 64);
            d += __shfl_xor(d, 32, 64);
            float q = 1.0f / (d + 1.0f);
            if (lane < 16) qb[lane] = q;
            // feature layout: m_f = sum_k q_k * mask[k][f]
            float4 q0 = *(const float4*)(qb + 0);
            float4 q1 = *(const float4*)(qb + 4);
            float4 q2 = *(const float4*)(qb + 8);
            float4 q3 = *(const float4*)(qb + 12);
            float m0, m1;
            m0  = q0.x*mk0[0]  + q0.y*mk0[1]  + q0.z*mk0[2]  + q0.w*mk0[3];
            m0 += q1.x*mk0[4]  + q1.y*mk0[5]  + q1.z*mk0[6]  + q1.w*mk0[7];
            m0 += q2.x*mk0[8]  + q2.y*mk0[9]  + q2.z*mk0[10] + q2.w*mk0[11];
            m0 += q3.x*mk0[12] + q3.y*mk0[13] + q3.z*mk0[14] + q3.w*mk0[15];
            m1  = q0.x*mk1[0]  + q0.y*mk1[1]  + q0.z*mk1[2]  + q0.w*mk1[3];
            m1 += q1.x*mk1[4]  + q1.y*mk1[5]  + q1.z*mk1[6]  + q1.w*mk1[7];
            m1 += q2.x*mk1[8]  + q2.y*mk1[9]  + q2.z*mk1[10] + q2.w*mk1[11];
            m1 += q3.x*mk1[12] + q3.y*mk1[13] + q3.z*mk1[14] + q3.w*mk1[15];
            acc0 += att * cn0 * m0;
            acc1 += att * cn1 * m1;
            attsum += att;
        }
        float inv = 1.0f / attsum;
        crow[lane]       = f2bf(s0);
        crow[lane + 64]  = f2bf(s1);
        crow[lane + 128] = f2bf(acc0 * inv);
        crow[lane + 192] = f2bf(acc1 * inv);
    }
    __syncthreads();

    // ---------------- phase B ----------------
    // A-fragments: A[m=l16][k = kk*32 + quad*8 + j]
    v8s afr[8];
    #pragma unroll
    for (int kk = 0; kk < 8; kk++)
        afr[kk] = *(const v8s*)(comb + l16 * CSTRIDE + kk * 32 + quad * 8);

    int Ntiles = (E + 15) >> 4;
    for (int nt = wave; nt < Ntiles; nt += 4) {
        const ushort_t* wrow = Wb + ((size_t)(nt * 16 + l16)) * 256 + quad * 8;
        v4f acc = {0.f, 0.f, 0.f, 0.f};
        #pragma unroll
        for (int kk = 0; kk < 8; kk++) {
            v8s bfr = *(const v8s*)(wrow + kk * 32);
            acc = __builtin_amdgcn_mfma_f32_16x16x32_bf16(afr[kk], bfr, acc, 0, 0, 0);
        }
        int gcol = nt * 16 + l16;
        if (gcol < E) {
            #pragma unroll
            for (int rr = 0; rr < 4; rr++) {
                int grow = b0 + quad * 4 + rr;
                if (grow < B)
                    out[(size_t)grow * E + gcol] = fmaxf(acc[rr], 0.f);
            }
        }
    }
}

extern "C" void kernel_launch(void* const* d_in, const int* in_sizes, int n_in,
                              void* d_out, int out_size, void* d_ws, size_t ws_size,
                              hipStream_t stream) {
    const int*   nodes        = (const int*)d_in[0];
    const int*   neigh_idx    = (const int*)d_in[1];
    const float* self_table   = (const float*)d_in[2];
    const float* neigh_table  = (const float*)d_in[3];
    const float* center       = (const float*)d_in[4];
    const float* cluster_mask = (const float*)d_in[5];
    const float* weight       = (const float*)d_in[6];
    const float* alpha        = (const float*)d_in[7];
    float* out = (float*)d_out;

    int B = in_sizes[0];
    int S = in_sizes[1] / B;
    int E = in_sizes[6] / (2 * FDIM);

    int Np = ((E + 15) / 16) * 16;
    ushort_t* Wb = (ushort_t*)d_ws;   // Np x 256 bf16

    long totalW = (long)Np * 256;
    long validW = (long)E * 256;
    int blksW = (int)((totalW + 1023) / 1024);
    pack_weight<<<blksW, 256, 0, stream>>>(weight, Wb, totalW, validW);

    int nblk = (B + 15) / 16;
    fused_agg<<<nblk, 256, 0, stream>>>(
        nodes, neigh_idx, self_table, neigh_table, center, cluster_mask, alpha,
        Wb, out, B, S, E);
}